// Round 4
// baseline (39.779 us; speedup 1.0000x reference)
//
#include <hip/hip_runtime.h>

// TransE 'rhs' scoring: pred[b,n] = MARGIN - || (s+r)[b] - e[n] ||_2
// B=32, N=200000, D=64, fp32 in/out.
//
// R3 post-mortem: LDS-pipe-bound -- 512 wave-uniform ds_read_b128 per
// row-pass x 12 waves/CU x ~12cyc ~= 31 us ~= measured 33.5 us.
// R4: q is wave-uniform -> move it to the SCALAR path. Prep kernel writes
// q=s+r (2048 f) + qnorm (32 f) to scratch; main kernel reads q with
// uniform addresses (compiler emits s_load through K$, q=8KB is K$-hot),
// FMA takes the SGPR operand directly. No LDS, no barrier in main kernel.
// Floors: HBM 12.2 us, VALU 5.4 us.

#define C4 16          // D/4 float4 chunks per row
#define MARGIN 9.0f
#define QN_OFF 2048    // qnorm offset (floats) inside scratch
#define WS_FLOATS 2080

__device__ float g_scratch[WS_FLOATS];   // fallback if d_ws too small

__global__ __launch_bounds__(256)
void transe_prep(const float* __restrict__ s_emb,
                 const float* __restrict__ rel_emb,
                 float* __restrict__ qbuf) {
    const int t = threadIdx.x;          // 0..255
    const float4* s4 = (const float4*)s_emb;
    const float4* r4 = (const float4*)rel_emb;
    float4* q4 = (float4*)qbuf;
#pragma unroll
    for (int k = 0; k < 2; ++k) {
        int idx = k * 256 + t;          // 512 float4 = 32 rows x 16 chunks
        float4 sv = s4[idx];
        float4 rv = r4[idx];
        float4 q;
        q.x = sv.x + rv.x; q.y = sv.y + rv.y;
        q.z = sv.z + rv.z; q.w = sv.w + rv.w;
        q4[idx] = q;
        float v = q.x*q.x + q.y*q.y + q.z*q.z + q.w*q.w;
        v += __shfl_xor(v, 1, 16);
        v += __shfl_xor(v, 2, 16);
        v += __shfl_xor(v, 4, 16);
        v += __shfl_xor(v, 8, 16);
        if ((t & 15) == 0) qbuf[QN_OFF + k * 16 + (t >> 4)] = v;  // b = idx/16
    }
}

__global__ __launch_bounds__(256)
void transe_main(const float* __restrict__ emb_e,
                 const float* __restrict__ qbuf,
                 float* __restrict__ out,
                 int N) {
    const long row = (long)blockIdx.x * 256 + threadIdx.x;
    if (row >= N) return;

    const float4* e4 = (const float4*)emb_e;
    const float4* q4 = (const float4*)qbuf;      // uniform reads -> s_load
    const float*  qn = qbuf + QN_OFF;

    float4 rv[C4];
#pragma unroll
    for (int c = 0; c < C4; ++c) rv[c] = e4[row * C4 + c];   // 16-deep MLP

    float4 en4 = {0.f, 0.f, 0.f, 0.f};
#pragma unroll
    for (int c = 0; c < C4; ++c) {
        en4.x = fmaf(rv[c].x, rv[c].x, en4.x);
        en4.y = fmaf(rv[c].y, rv[c].y, en4.y);
        en4.z = fmaf(rv[c].z, rv[c].z, en4.z);
        en4.w = fmaf(rv[c].w, rv[c].w, en4.w);
    }
    const float en = (en4.x + en4.y) + (en4.z + en4.w);

    float* op = out + row;
#pragma unroll
    for (int b = 0; b < 32; ++b) {
        float4 d4 = {0.f, 0.f, 0.f, 0.f};
#pragma unroll
        for (int c = 0; c < C4; ++c) {
            float4 qv = q4[b * C4 + c];   // wave-uniform -> SGPR operand
            d4.x = fmaf(qv.x, rv[c].x, d4.x);
            d4.y = fmaf(qv.y, rv[c].y, d4.y);
            d4.z = fmaf(qv.z, rv[c].z, d4.z);
            d4.w = fmaf(qv.w, rv[c].w, d4.w);
        }
        const float dot = (d4.x + d4.y) + (d4.z + d4.w);
        const float d2 = fmaxf(fmaf(-2.f, dot, qn[b] + en), 0.f);
        op[(long)b * N] = MARGIN - sqrtf(d2);   // 64 consecutive floats/wave
    }
}

extern "C" void kernel_launch(void* const* d_in, const int* in_sizes, int n_in,
                              void* d_out, int out_size, void* d_ws, size_t ws_size,
                              hipStream_t stream) {
    const float* s = (const float*)d_in[0];
    const float* r = (const float*)d_in[1];
    const float* e = (const float*)d_in[2];
    float* out = (float*)d_out;

    const int N = in_sizes[2] / 64;            // 200000

    float* qbuf;
    if (ws_size >= WS_FLOATS * sizeof(float)) {
        qbuf = (float*)d_ws;
    } else {
        void* p = nullptr;
        hipGetSymbolAddress(&p, HIP_SYMBOL(g_scratch));  // no alloc; capture-safe
        qbuf = (float*)p;
    }

    transe_prep<<<1, 256, 0, stream>>>(s, r, qbuf);
    const int grid = (N + 255) / 256;          // 782 blocks x 256 threads
    transe_main<<<grid, 256, 0, stream>>>(e, qbuf, out, N);
}

// Round 5
// 34.167 us; speedup vs baseline: 1.1643x; 1.1643x over previous
//
#include <hip/hip_runtime.h>

// TransE 'rhs': pred[b,n] = MARGIN - ||(s+r)[b] - e[n]||_2.  B=32,N=200k,D=64 fp32.
//
// R3/R4 post-mortem: q re-fetched per (b,c) per wave (LDS or K$) = fetch-pipe
// bound ~31us. R5: MFMA. q lives in VGPR A-fragments, built once per wave,
// reused across the whole n-sweep. Split-bf16 (hi+lo) keeps dot error ~3e-4:
// dot ~= qh.eh + ql.eh + qh.el. norms in fp32. No LDS, no barriers.
// Tile: 32x32 output per mfma_f32_32x32x16_bf16, K=64 -> 4 k-steps, 12 MFMA.
// Wave owns 64 rows (2 tiles); 3125 waves (~12/CU); every e byte read once.

#define MARGIN 9.0f

typedef __attribute__((ext_vector_type(8)))  short bf16x8;
typedef __attribute__((ext_vector_type(16))) float f32x16;

__device__ __forceinline__ unsigned f2bf(float f) {   // fp32 -> bf16 bits, RNE
    unsigned u = __float_as_uint(f);
    return (u + 0x7FFFu + ((u >> 16) & 1u)) >> 16;
}

__global__ __launch_bounds__(256)
void transe_mfma(const float* __restrict__ s_emb,
                 const float* __restrict__ rel_emb,
                 const float* __restrict__ emb_e,
                 float* __restrict__ out,
                 int N, int nwaves) {
    const int t = threadIdx.x;
    const int wid = blockIdx.x * 4 + (t >> 6);
    if (wid >= nwaves) return;
    const int l    = t & 63;
    const int m    = l & 31;      // A-row / B-col within tile
    const int half = l >> 5;      // k-half selector

    const float4* s4 = (const float4*)s_emb;
    const float4* r4 = (const float4*)rel_emb;
    const float4* e4 = (const float4*)emb_e;

    // ---- A operand: q = s + r as bf16 hi/lo fragments; k = 16*tt + 8*half + i.
    bf16x8 qh[4], ql[4];
    float qn_part = 0.f;
#pragma unroll
    for (int tt = 0; tt < 4; ++tt) {
        float qf[8];
#pragma unroll
        for (int c = 0; c < 2; ++c) {
            int idx = m * 16 + half * 2 + tt * 4 + c;    // float4 units
            float4 sv = s4[idx], rv = r4[idx];
            qf[c*4+0] = sv.x + rv.x; qf[c*4+1] = sv.y + rv.y;
            qf[c*4+2] = sv.z + rv.z; qf[c*4+3] = sv.w + rv.w;
        }
#pragma unroll
        for (int i = 0; i < 8; ++i) {
            qn_part = fmaf(qf[i], qf[i], qn_part);
            unsigned h = f2bf(qf[i]);
            qh[tt][i] = (short)h;
            ql[tt][i] = (short)f2bf(qf[i] - __uint_as_float(h << 16));
        }
    }
    // qnorm for row m (both k-halves), then broadcast all 32 to SGPRs.
    float qn_own = qn_part + __shfl_xor(qn_part, 32);
    float qn_all[32];
#pragma unroll
    for (int i = 0; i < 32; ++i)
        qn_all[i] = __uint_as_float(
            __builtin_amdgcn_readlane(__float_as_uint(qn_own), i));

    // ---- Two 32-row tiles per wave.
    const long base_n = (long)wid * 64;
#pragma unroll
    for (int j = 0; j < 2; ++j) {
        const long n0 = base_n + j * 32;

        float ef[32];                 // lane's 32 fp32 elements of row n0+m
        float en_part = 0.f;
#pragma unroll
        for (int tt = 0; tt < 4; ++tt)
#pragma unroll
            for (int c = 0; c < 2; ++c) {
                float4 ev = e4[(n0 + m) * 16 + half * 2 + tt * 4 + c];
                ef[tt*8 + c*4 + 0] = ev.x; ef[tt*8 + c*4 + 1] = ev.y;
                ef[tt*8 + c*4 + 2] = ev.z; ef[tt*8 + c*4 + 3] = ev.w;
            }

        f32x16 acc;
#pragma unroll
        for (int i = 0; i < 16; ++i) acc[i] = 0.f;

#pragma unroll
        for (int tt = 0; tt < 4; ++tt) {
            bf16x8 eh, el;
#pragma unroll
            for (int i = 0; i < 8; ++i) {
                float f = ef[tt*8 + i];
                en_part = fmaf(f, f, en_part);
                unsigned h = f2bf(f);
                eh[i] = (short)h;
                el[i] = (short)f2bf(f - __uint_as_float(h << 16));
            }
            acc = __builtin_amdgcn_mfma_f32_32x32x16_bf16(qh[tt], eh, acc, 0, 0, 0);
            acc = __builtin_amdgcn_mfma_f32_32x32x16_bf16(ql[tt], eh, acc, 0, 0, 0);
            acc = __builtin_amdgcn_mfma_f32_32x32x16_bf16(qh[tt], el, acc, 0, 0, 0);
        }

        const float en_own = en_part + __shfl_xor(en_part, 32);  // row n0+m
        const long  col    = n0 + m;
#pragma unroll
        for (int r = 0; r < 16; ++r) {
            const int  b_lo = (r & 3) + 8 * (r >> 2);
            const float qn_v = half ? qn_all[b_lo + 4] : qn_all[b_lo];
            const float d2   = fmaxf(fmaf(-2.f, acc[r], qn_v + en_own), 0.f);
            out[(long)(b_lo + 4 * half) * N + col] = MARGIN - sqrtf(d2);
        }
    }
}

extern "C" void kernel_launch(void* const* d_in, const int* in_sizes, int n_in,
                              void* d_out, int out_size, void* d_ws, size_t ws_size,
                              hipStream_t stream) {
    const float* s = (const float*)d_in[0];
    const float* r = (const float*)d_in[1];
    const float* e = (const float*)d_in[2];
    float* out = (float*)d_out;

    const int N = in_sizes[2] / 64;        // 200000
    const int nwaves = N / 64;             // 3125 (N % 64 == 0)
    const int grid = (nwaves + 3) / 4;     // 782 blocks x 256 threads

    transe_mfma<<<grid, 256, 0, stream>>>(s, r, e, out, N, nwaves);
}

// Round 6
// 33.184 us; speedup vs baseline: 1.1988x; 1.0296x over previous
//
#include <hip/hip_runtime.h>

// TransE 'rhs': pred[b,n] = MARGIN - ||(s+r)[b] - e[n]||_2. B=32,N=200k,D=64 fp32.
//
// R5 post-mortem: (a) WRITE amplified 2x (128B store segments), (b) ALL rounds'
// e-loads were lane-stride-256B -> 64 cache lines per VMEM instr -> TA-bound
// ~2TB/s ceiling. R6: fully coalesced global traffic.
//  - e staged to LDS via global_load_lds width=16 (1KB/instr, 8 lines), source
//    pre-swizzled with y ^= ((row&7)<<4) (line-preserving) so swizzled
//    ds_read_b128 fragment reads are bank-balanced (rule #21 both-sides swz).
//  - q (s,r) staged the same way through the wave's own slices, fragments
//    packed once into VGPRs (hi/lo bf16 split, 12 MFMA per 32x32 tile).
//  - preds staged to LDS [32][64] then stored 1KB/instr (4x 256B segments).
//  - counted vmcnt: issue j0+j1 stages, vmcnt(8) -> compute j0, vmcnt(0) -> j1.
// Per-wave LDS 16KB, block 64KB -> 2 blocks/CU, 8 waves/CU. No barriers.

#define MARGIN 9.0f

typedef __attribute__((ext_vector_type(8)))  short bf16x8;
typedef __attribute__((ext_vector_type(16))) float f32x16;

typedef __attribute__((address_space(3))) void        lds_vp;
typedef __attribute__((address_space(1))) const void  glb_vp;

__device__ __forceinline__ unsigned f2bf(float f) {   // fp32 -> bf16 bits, RNE
    unsigned u = __float_as_uint(f);
    return (u + 0x7FFFu + ((u >> 16) & 1u)) >> 16;
}

// Stage one 32-row x 256B tile (8KB) global->LDS, coalesced 8 x 1KB.
// Physical LDS slot p holds global byte y = p ^ (((p>>8)&7)<<4): involution,
// flips byte bits 4-6 only -> stays inside the row's own 128B lines.
__device__ __forceinline__ void stage_tile(const char* __restrict__ g,
                                           char* l, int lane) {
#pragma unroll
    for (int k = 0; k < 8; ++k) {
        unsigned p = (unsigned)(k * 1024 + lane * 16);
        unsigned y = p ^ (((p >> 8) & 7u) << 4);
        __builtin_amdgcn_global_load_lds((glb_vp*)(g + y),
                                         (lds_vp*)(l + k * 1024), 16, 0, 0);
    }
}

__global__ __launch_bounds__(256)
void transe_mfma2(const float* __restrict__ s_emb,
                  const float* __restrict__ rel_emb,
                  const float* __restrict__ emb_e,
                  float* __restrict__ out,
                  int N, int nwaves) {
    __shared__ char lds[65536];
    const int t    = threadIdx.x;
    const int w    = t >> 6;
    const int lane = t & 63;
    char* A = lds + w * 16384;
    char* B = A + 8192;

    const int wid = blockIdx.x * 4 + w;
    if (wid >= nwaves) return;          // no barriers anywhere: safe early-out

    const int m    = lane & 31;         // fragment row/col within tile
    const int half = lane >> 5;         // k-half selector
    const unsigned fr_base = (unsigned)(m * 256 + half * 32);
    const unsigned fr_sw   = ((unsigned)(m & 7)) << 4;

    // ---- q prologue: stage s->A, r->B (coalesced), build A-fragments.
    stage_tile((const char*)s_emb,   A, lane);
    stage_tile((const char*)rel_emb, B, lane);
    asm volatile("s_waitcnt vmcnt(0)" ::: "memory");

    bf16x8 qh[4], ql[4];
    float qn_part = 0.f;
#pragma unroll
    for (int tt = 0; tt < 4; ++tt) {
        unsigned p = (fr_base + tt * 64) ^ fr_sw;
        float4 s0 = *(const float4*)(A + p);
        float4 s1 = *(const float4*)(A + (p ^ 16));
        float4 r0 = *(const float4*)(B + p);
        float4 r1 = *(const float4*)(B + (p ^ 16));
        float qf[8] = { s0.x + r0.x, s0.y + r0.y, s0.z + r0.z, s0.w + r0.w,
                        s1.x + r1.x, s1.y + r1.y, s1.z + r1.z, s1.w + r1.w };
#pragma unroll
        for (int i = 0; i < 8; ++i) {
            qn_part = fmaf(qf[i], qf[i], qn_part);
            unsigned h = f2bf(qf[i]);
            qh[tt][i] = (short)h;
            ql[tt][i] = (short)f2bf(qf[i] - __uint_as_float(h << 16));
        }
    }
    float qn_own = qn_part + __shfl_xor(qn_part, 32);   // ||q_m||^2
    float qn_all[32];
#pragma unroll
    for (int i = 0; i < 32; ++i)
        qn_all[i] = __uint_as_float(
            __builtin_amdgcn_readlane(__float_as_uint(qn_own), i));

    // q LDS reads must retire before the e-DMA overwrites A/B.
    asm volatile("s_waitcnt lgkmcnt(0)" ::: "memory");

    // ---- e stage: j0 -> A, j1 -> B, both in flight.
    const char* ebase = (const char*)emb_e + (size_t)wid * 16384;  // 64 rows
    stage_tile(ebase,        A, lane);
    stage_tile(ebase + 8192, B, lane);

    float* outT = (float*)A;            // [32 b][64 n] staging (reuses A)
#pragma unroll
    for (int j = 0; j < 2; ++j) {
        if (j == 0) { asm volatile("s_waitcnt vmcnt(8)" ::: "memory"); }
        else        { asm volatile("s_waitcnt vmcnt(0)" ::: "memory"); }
        const char* L = j ? B : A;

        f32x16 acc;
#pragma unroll
        for (int i = 0; i < 16; ++i) acc[i] = 0.f;
        float en_part = 0.f;

#pragma unroll
        for (int tt = 0; tt < 4; ++tt) {
            unsigned p = (fr_base + tt * 64) ^ fr_sw;
            float4 e0 = *(const float4*)(L + p);
            float4 e1 = *(const float4*)(L + (p ^ 16));
            float ef[8] = { e0.x, e0.y, e0.z, e0.w, e1.x, e1.y, e1.z, e1.w };
            bf16x8 eh, el;
#pragma unroll
            for (int i = 0; i < 8; ++i) {
                en_part = fmaf(ef[i], ef[i], en_part);
                unsigned h = f2bf(ef[i]);
                eh[i] = (short)h;
                el[i] = (short)f2bf(ef[i] - __uint_as_float(h << 16));
            }
            acc = __builtin_amdgcn_mfma_f32_32x32x16_bf16(qh[tt], eh, acc, 0, 0, 0);
            acc = __builtin_amdgcn_mfma_f32_32x32x16_bf16(ql[tt], eh, acc, 0, 0, 0);
            acc = __builtin_amdgcn_mfma_f32_32x32x16_bf16(qh[tt], el, acc, 0, 0, 0);
        }
        const float en = en_part + __shfl_xor(en_part, 32);  // ||e_row||^2

        // preds -> outT (j0's A data already consumed; j1 reads only B).
#pragma unroll
        for (int r = 0; r < 16; ++r) {
            const int  b_lo = (r & 3) + 8 * (r >> 2);
            const float qn_v = half ? qn_all[b_lo + 4] : qn_all[b_lo];
            const float d2   = fmaxf(fmaf(-2.f, acc[r], qn_v + en), 0.f);
            outT[(b_lo + 4 * half) * 64 + j * 32 + m] = MARGIN - sqrtf(d2);
        }
    }

    // ---- Coalesced out: 8 instrs x 1KB (4 rows x 256B-aligned segments).
    const long n_base = (long)wid * 64;
#pragma unroll
    for (int k = 0; k < 8; ++k) {
        const int row_b = 4 * k + (lane >> 4);
        const int c0    = (lane & 15) * 4;
        float4 v = *(const float4*)(outT + row_b * 64 + c0);
        *(float4*)(out + (long)row_b * N + n_base + c0) = v;
    }
}

extern "C" void kernel_launch(void* const* d_in, const int* in_sizes, int n_in,
                              void* d_out, int out_size, void* d_ws, size_t ws_size,
                              hipStream_t stream) {
    const float* s = (const float*)d_in[0];
    const float* r = (const float*)d_in[1];
    const float* e = (const float*)d_in[2];
    float* out = (float*)d_out;

    const int N = in_sizes[2] / 64;        // 200000
    const int nwaves = N / 64;             // 3125 tiles of 64 rows
    const int grid = (nwaves + 3) / 4;     // 782 blocks x 256 threads

    transe_mfma2<<<grid, 256, 0, stream>>>(s, r, e, out, N, nwaves);
}

// Round 7
// 29.130 us; speedup vs baseline: 1.3656x; 1.1391x over previous
//
#include <hip/hip_runtime.h>

// TransE 'rhs': pred[b,n] = MARGIN - ||(s+r)[b] - e[n]||_2. B=32,N=200k,D=64 fp32.
//
// R6 post-mortem: three different structures all pin at ~33us with all pipes
// idle -> the common flaw is schedule shape: one tile per short-lived wave,
// full vmcnt(0) drains, in-flight bytes collapse to zero repeatedly.
// R7: persistent 3-tile waves, double-buffered LDS (2x16KB), counted vmcnt
// (16/24/8 - never 0 mid-pipeline), q-fragments built once per wave and
// amortized over 3 tiles. 1042 blocks x 64 thr; loads stay continuously in
// flight (~128KB/CU). Dummy 3126th tile keeps waits wave-uniform.

#define MARGIN 9.0f

typedef __attribute__((ext_vector_type(8)))  short bf16x8;
typedef __attribute__((ext_vector_type(16))) float f32x16;

typedef __attribute__((address_space(3))) void        lds_vp;
typedef __attribute__((address_space(1))) const void  glb_vp;

__global__ __launch_bounds__(64)
void transe7(const float* __restrict__ s_emb,
             const float* __restrict__ rel_emb,
             const float* __restrict__ emb_e,
             float* __restrict__ out, int N)
{
    __shared__ char lds[32768];
    const int  lane  = threadIdx.x & 63;
    const int  m     = lane & 31;
    const int  half  = lane >> 5;
    const int  ntile = N >> 6;                  // 3125
    const long base  = (long)blockIdx.x * 3;

    // ---------- q fragments (hi + exact-residual bf16) + qnorm ----------
    const float4* s4 = (const float4*)s_emb;
    const float4* r4 = (const float4*)rel_emb;
    bf16x8 qh[4], ql[4];
    float qn_part = 0.f;
#pragma unroll
    for (int tt = 0; tt < 4; ++tt) {
        float qf[8];
#pragma unroll
        for (int c = 0; c < 2; ++c) {
            const int idx = m*16 + tt*4 + half*2 + c;
            float4 sv = s4[idx], rv = r4[idx];
            qf[c*4+0] = sv.x+rv.x; qf[c*4+1] = sv.y+rv.y;
            qf[c*4+2] = sv.z+rv.z; qf[c*4+3] = sv.w+rv.w;
        }
#pragma unroll
        for (int i = 0; i < 8; ++i) {
            const float f = qf[i];
            qn_part = fmaf(f, f, qn_part);
            const unsigned u = __float_as_uint(f);
            qh[tt][i] = (short)(u >> 16);                      // trunc hi
            const float lo = f - __uint_as_float(u & 0xFFFF0000u);  // exact
            ql[tt][i] = (short)(__float_as_uint(lo) >> 16);
        }
    }
    const float qn_own = qn_part + __shfl_xor(qn_part, 32);
    float qn_all[32];
#pragma unroll
    for (int i = 0; i < 32; ++i)
        qn_all[i] = __uint_as_float(
            __builtin_amdgcn_readlane(__float_as_uint(qn_own), i));
    asm volatile("" ::: "memory");   // pin q-loads (+their waits) before DMAs

    // ---------- tile pipeline ----------
    char* const b0 = lds;
    char* const b1 = lds + 16384;
    const char* const ebase = (const char*)emb_e;

    auto stage = [&](long t, char* l) {          // 16 x 1KB DMA, swizzled src
        const long ts = (t < ntile) ? t : (ntile - 1);
        const char* g = ebase + ts * 16384;
#pragma unroll
        for (int k = 0; k < 16; ++k) {
            const unsigned p = (unsigned)(k*1024 + lane*16);
            const unsigned y = p ^ (((p >> 8) & 7u) << 4);   // line-preserving
            __builtin_amdgcn_global_load_lds((glb_vp*)(g + y),
                                             (lds_vp*)(l + k*1024), 16, 0, 0);
        }
    };

    const unsigned fr_base = (unsigned)(m*256 + half*32);
    const unsigned fr_sw   = ((unsigned)(m & 7)) << 4;

    auto do_tile = [&](char* L) {
#pragma unroll
        for (int j = 0; j < 2; ++j) {
            const char* Lj = L + j*8192;
            f32x16 acc;
#pragma unroll
            for (int i = 0; i < 16; ++i) acc[i] = 0.f;
            float en_part = 0.f;
#pragma unroll
            for (int tt = 0; tt < 4; ++tt) {
                const unsigned p = (fr_base + tt*64) ^ fr_sw;
                float4 e0 = *(const float4*)(Lj + p);
                float4 e1 = *(const float4*)(Lj + (p ^ 16));
                const float ef[8] = {e0.x,e0.y,e0.z,e0.w, e1.x,e1.y,e1.z,e1.w};
                bf16x8 eh, el;
#pragma unroll
                for (int i = 0; i < 8; ++i) {
                    const float f = ef[i];
                    en_part = fmaf(f, f, en_part);
                    const unsigned u = __float_as_uint(f);
                    eh[i] = (short)(u >> 16);
                    const float lo = f - __uint_as_float(u & 0xFFFF0000u);
                    el[i] = (short)(__float_as_uint(lo) >> 16);
                }
                acc = __builtin_amdgcn_mfma_f32_32x32x16_bf16(qh[tt], eh, acc, 0,0,0);
                acc = __builtin_amdgcn_mfma_f32_32x32x16_bf16(ql[tt], eh, acc, 0,0,0);
                acc = __builtin_amdgcn_mfma_f32_32x32x16_bf16(qh[tt], el, acc, 0,0,0);
            }
            const float en = en_part + __shfl_xor(en_part, 32);
            float* outT = (float*)L;             // overlays consumed e-half
#pragma unroll
            for (int r = 0; r < 16; ++r) {
                const int bb = (r & 3) + 8*(r >> 2);
                const int b  = bb + 4*half;
                const float qn_v = half ? qn_all[bb + 4] : qn_all[bb];
                const float d2 = fmaxf(fmaf(-2.f, acc[r], qn_v + en), 0.f);
                outT[b*64 + j*32 + m] = MARGIN - sqrtf(d2);
            }
        }
    };

    auto store_tile = [&](char* L, long tile) {  // 8 x 1KB (4x256B segments)
        if (tile >= ntile) return;
        const float* outT = (const float*)L;
        const long nb = tile * 64;
#pragma unroll
        for (int k = 0; k < 8; ++k) {
            const int rb = 4*k + (lane >> 4);
            const int c0 = (lane & 15) * 4;
            const float4 v = *(const float4*)(outT + rb*64 + c0);
            *(float4*)(out + (size_t)rb * N + nb + c0) = v;
        }
    };

    // prologue: both buffers' DMAs in flight
    stage(base + 0, b0);
    stage(base + 1, b1);

    // iter 0: wait only for buf0's 16 loads (buf1's stay outstanding)
    asm volatile("s_waitcnt vmcnt(16)" ::: "memory");
    do_tile(b0);
    store_tile(b0, base + 0);
    asm volatile("s_waitcnt lgkmcnt(0)" ::: "memory");  // outT reads done
    stage(base + 2, b0);

    // iter 1: outstanding = DMA1(16)+stores0(8)+DMA2(16)=40 -> retire DMA1
    asm volatile("s_waitcnt vmcnt(24)" ::: "memory");
    do_tile(b1);
    store_tile(b1, base + 1);

    // iter 2: outstanding = stores0(8)+DMA2(16)+stores1(8)=32 -> retire DMA2
    asm volatile("s_waitcnt vmcnt(8)" ::: "memory");
    do_tile(b0);
    store_tile(b0, base + 2);
}

extern "C" void kernel_launch(void* const* d_in, const int* in_sizes, int n_in,
                              void* d_out, int out_size, void* d_ws, size_t ws_size,
                              hipStream_t stream) {
    const float* s = (const float*)d_in[0];
    const float* r = (const float*)d_in[1];
    const float* e = (const float*)d_in[2];
    float* out = (float*)d_out;

    const int N = in_sizes[2] / 64;            // 200000
    const int ntile = N / 64;                  // 3125
    const int grid = (ntile + 2) / 3;          // 1042 blocks x 64 threads

    transe7<<<grid, 64, 0, stream>>>(s, r, e, out, N);
}

// Round 8
// 27.947 us; speedup vs baseline: 1.4234x; 1.0423x over previous
//
#include <hip/hip_runtime.h>

// TransE 'rhs': pred[b,n] = MARGIN - ||(s+r)[b] - e[n]||_2. B=32,N=200k,D=64 fp32.
//
// R7 post-mortem: five structures all land 29-34us while every pipe reads
// ~idle and static per-pipe costs are <=6us -> limiter = per-wave critical
// path at ~1 wave/SIMD (LDS caps 5 waves/CU). R8: halve the path, keep R7's
// schedule exactly:
//  - e-side hi-only bf16 (q stays exact hi+lo, built once in prologue):
//    dot ~= (qh+ql).eh = q.eh; dropped term q.e_lo ~0.1 in d2 (thr 0.21 on
//    pred => ~4x headroom). 16 MFMA/tile (was 24), dep-chain 2 (was 3).
//  - bf16 pair packing via one v_perm_b32 per 2 floats (was shift/sub/shift).
// Persistent 3-tile waves, dbuf LDS 2x16KB, counted vmcnt 16/24/8, 256B-
// aligned store segments -- all unchanged from R7.

#define MARGIN 9.0f

typedef __attribute__((ext_vector_type(8)))  short bf16x8;
typedef __attribute__((ext_vector_type(16))) float f32x16;
typedef __attribute__((ext_vector_type(4)))  unsigned int u32x4;

typedef __attribute__((address_space(3))) void        lds_vp;
typedef __attribute__((address_space(1))) const void  glb_vp;

__global__ __launch_bounds__(64)
void transe8(const float* __restrict__ s_emb,
             const float* __restrict__ rel_emb,
             const float* __restrict__ emb_e,
             float* __restrict__ out, int N)
{
    __shared__ char lds[32768];
    const int  lane  = threadIdx.x & 63;
    const int  m     = lane & 31;
    const int  half  = lane >> 5;
    const int  ntile = N >> 6;                  // 3125
    const long base  = (long)blockIdx.x * 3;

    // ---------- q fragments (hi + exact-residual bf16) + qnorm ----------
    const float4* s4 = (const float4*)s_emb;
    const float4* r4 = (const float4*)rel_emb;
    bf16x8 qh[4], ql[4];
    float qn_part = 0.f;
#pragma unroll
    for (int tt = 0; tt < 4; ++tt) {
        float qf[8];
#pragma unroll
        for (int c = 0; c < 2; ++c) {
            const int idx = m*16 + tt*4 + half*2 + c;
            float4 sv = s4[idx], rv = r4[idx];
            qf[c*4+0] = sv.x+rv.x; qf[c*4+1] = sv.y+rv.y;
            qf[c*4+2] = sv.z+rv.z; qf[c*4+3] = sv.w+rv.w;
        }
#pragma unroll
        for (int i = 0; i < 8; ++i) {
            const float f = qf[i];
            qn_part = fmaf(f, f, qn_part);
            const unsigned u = __float_as_uint(f);
            qh[tt][i] = (short)(u >> 16);                      // trunc hi
            const float lo = f - __uint_as_float(u & 0xFFFF0000u);  // exact
            ql[tt][i] = (short)(__float_as_uint(lo) >> 16);
        }
    }
    const float qn_own = qn_part + __shfl_xor(qn_part, 32);
    float qn_all[32];
#pragma unroll
    for (int i = 0; i < 32; ++i)
        qn_all[i] = __uint_as_float(
            __builtin_amdgcn_readlane(__float_as_uint(qn_own), i));
    asm volatile("" ::: "memory");   // pin q-loads (+their waits) before DMAs

    // ---------- tile pipeline ----------
    char* const b0 = lds;
    char* const b1 = lds + 16384;
    const char* const ebase = (const char*)emb_e;

    auto stage = [&](long t, char* l) {          // 16 x 1KB DMA, swizzled src
        const long ts = (t < ntile) ? t : (ntile - 1);
        const char* g = ebase + ts * 16384;
#pragma unroll
        for (int k = 0; k < 16; ++k) {
            const unsigned p = (unsigned)(k*1024 + lane*16);
            const unsigned y = p ^ (((p >> 8) & 7u) << 4);   // line-preserving
            __builtin_amdgcn_global_load_lds((glb_vp*)(g + y),
                                             (lds_vp*)(l + k*1024), 16, 0, 0);
        }
    };

    const unsigned fr_base = (unsigned)(m*256 + half*32);
    const unsigned fr_sw   = ((unsigned)(m & 7)) << 4;

    auto do_tile = [&](char* L) {
#pragma unroll
        for (int j = 0; j < 2; ++j) {
            const char* Lj = L + j*8192;
            f32x16 acc;
#pragma unroll
            for (int i = 0; i < 16; ++i) acc[i] = 0.f;
            float en_part = 0.f;
#pragma unroll
            for (int tt = 0; tt < 4; ++tt) {
                const unsigned p = (fr_base + tt*64) ^ fr_sw;
                float4 e0 = *(const float4*)(Lj + p);
                float4 e1 = *(const float4*)(Lj + (p ^ 16));
                // ||e||^2 partials in fp32
                en_part = fmaf(e0.x, e0.x, en_part);
                en_part = fmaf(e0.y, e0.y, en_part);
                en_part = fmaf(e0.z, e0.z, en_part);
                en_part = fmaf(e0.w, e0.w, en_part);
                en_part = fmaf(e1.x, e1.x, en_part);
                en_part = fmaf(e1.y, e1.y, en_part);
                en_part = fmaf(e1.z, e1.z, en_part);
                en_part = fmaf(e1.w, e1.w, en_part);
                // pack hi-bf16 pairs: one v_perm per 2 floats
                u32x4 ep;
                ep[0] = __builtin_amdgcn_perm(__float_as_uint(e0.y),
                                              __float_as_uint(e0.x), 0x07060302u);
                ep[1] = __builtin_amdgcn_perm(__float_as_uint(e0.w),
                                              __float_as_uint(e0.z), 0x07060302u);
                ep[2] = __builtin_amdgcn_perm(__float_as_uint(e1.y),
                                              __float_as_uint(e1.x), 0x07060302u);
                ep[3] = __builtin_amdgcn_perm(__float_as_uint(e1.w),
                                              __float_as_uint(e1.z), 0x07060302u);
                const bf16x8 eh = __builtin_bit_cast(bf16x8, ep);
                acc = __builtin_amdgcn_mfma_f32_32x32x16_bf16(qh[tt], eh, acc, 0,0,0);
                acc = __builtin_amdgcn_mfma_f32_32x32x16_bf16(ql[tt], eh, acc, 0,0,0);
            }
            const float en = en_part + __shfl_xor(en_part, 32);
            float* outT = (float*)L;             // overlays consumed e-half
#pragma unroll
            for (int r = 0; r < 16; ++r) {
                const int bb = (r & 3) + 8*(r >> 2);
                const int b  = bb + 4*half;
                const float qn_v = half ? qn_all[bb + 4] : qn_all[bb];
                const float d2 = fmaxf(fmaf(-2.f, acc[r], qn_v + en), 0.f);
                outT[b*64 + j*32 + m] = MARGIN - sqrtf(d2);
            }
        }
    };

    auto store_tile = [&](char* L, long tile) {  // 8 x 1KB (4x256B segments)
        if (tile >= ntile) return;
        const float* outT = (const float*)L;
        const long nb = tile * 64;
#pragma unroll
        for (int k = 0; k < 8; ++k) {
            const int rb = 4*k + (lane >> 4);
            const int c0 = (lane & 15) * 4;
            const float4 v = *(const float4*)(outT + rb*64 + c0);
            *(float4*)(out + (size_t)rb * N + nb + c0) = v;
        }
    };

    // prologue: both buffers' DMAs in flight
    stage(base + 0, b0);
    stage(base + 1, b1);

    // iter 0: wait only for buf0's 16 loads (buf1's stay outstanding)
    asm volatile("s_waitcnt vmcnt(16)" ::: "memory");
    do_tile(b0);
    store_tile(b0, base + 0);
    asm volatile("s_waitcnt lgkmcnt(0)" ::: "memory");  // outT reads done
    stage(base + 2, b0);

    // iter 1: outstanding = DMA1(16)+stores0(8)+DMA2(16)=40 -> retire DMA1
    asm volatile("s_waitcnt vmcnt(24)" ::: "memory");
    do_tile(b1);
    store_tile(b1, base + 1);

    // iter 2: outstanding = stores0(8)+DMA2(16)+stores1(8)=32 -> retire DMA2
    asm volatile("s_waitcnt vmcnt(8)" ::: "memory");
    do_tile(b0);
    store_tile(b0, base + 2);
}

extern "C" void kernel_launch(void* const* d_in, const int* in_sizes, int n_in,
                              void* d_out, int out_size, void* d_ws, size_t ws_size,
                              hipStream_t stream) {
    const float* s = (const float*)d_in[0];
    const float* r = (const float*)d_in[1];
    const float* e = (const float*)d_in[2];
    float* out = (float*)d_out;

    const int N = in_sizes[2] / 64;            // 200000
    const int ntile = N / 64;                  // 3125
    const int grid = (ntile + 2) / 3;          // 1042 blocks x 64 threads

    transe8<<<grid, 64, 0, stream>>>(s, r, e, out, N);
}